// Round 7
// baseline (113.148 us; speedup 1.0000x reference)
//
#include <hip/hip_runtime.h>

#define N 1024
#define D 256

// ---------------- prep ----------------
// Layout: msT2[(g*N+row)*2+b]: b=0 -> (mu_{2g},mu_{2g+1})*rden, b=1 -> (sig_{2g},sig_{2g+1})
// so pair's float4 read = (mu0, mu1, sig0, sig1) in natural 64-bit halves.
#define RI 8
#define LDW 260  // padded LDS row stride: %4==0 (float4 stores ok), +4 banks/row

__global__ __launch_bounds__(256) void prep3(
    const float* __restrict__ muX, const float* __restrict__ ls,
    float2* __restrict__ msT2) {
  const int i0 = blockIdx.x * RI;
  const int t = threadIdx.x;
  __shared__ float smu[RI][LDW];
  __shared__ float ssg[RI][LDW];
  __shared__ float sred[RI][32];
  __shared__ float rden[RI];
  const float4* mu4 = (const float4*)(muX + (size_t)i0 * D);
  const float4* ls4 = (const float4*)(ls + (size_t)i0 * D);
#pragma unroll
  for (int u = 0; u < 2; ++u) {
    const int idx = u * 256 + t;  // float4 index within the 8x256 row block
    const int row = idx >> 6, c4 = idx & 63;
    const float4 v = mu4[idx];
    *(float4*)&smu[row][c4 * 4] = v;
    const float4 e = ls4[idx];
    float4 x;
    x.x = __expf(e.x) + 5e-11f; x.y = __expf(e.y) + 5e-11f;  // eps folded
    x.z = __expf(e.z) + 5e-11f; x.w = __expf(e.w) + 5e-11f;
    *(float4*)&ssg[row][c4 * 4] = x;
  }
  __syncthreads();
  {
    const int r = t >> 5, q = t & 31;  // 32 lanes per row
    float s = 0.f;
#pragma unroll
    for (int k = 0; k < 8; ++k) {
      const float v = smu[r][q + 32 * k];
      s = fmaf(v, v, s);
    }
    sred[r][q] = s;
  }
  __syncthreads();
  if (t < RI) {
    float tot = 0.f;
    for (int u = 0; u < 32; ++u) tot += sred[t][u];
    rden[t] = 1.0f / fmaxf(sqrtf(tot), 1e-12f);  // F.normalize eps
  }
  __syncthreads();
#pragma unroll
  for (int pass = 0; pass < 8; ++pass) {
    const int f = pass * 256 + t;
    const int b = f & 1, il = (f >> 1) & 7, g = f >> 4;
    const float* src = b ? &ssg[il][0] : &smu[il][0];
    const float sc = b ? 1.0f : rden[il];
    msT2[((size_t)g * N + i0 + il) * 2 + b] =
        make_float2(src[2 * g] * sc, src[2 * g + 1] * sc);
  }
}

// ---------------- pair ----------------
// Triangular 2x128 tiles, D-SPLIT: 2304 blocks x 4 waves (256 thr).
// Waves 0-1 (h=0) do d[0,128), waves 2-3 (h=1) do d[128,256) of the SAME
// 2x128 tile; both acc and the ln-term are additive over d -> exact split,
// combined via 1KB LDS. Doubles resident waves (R1-R5: occupancy pinned
// ~27%, VALUBusy 40% at halved issue count -> stall-bound, TLP is the lever).
// i-side wave-uniform s_loads from msT4 (R3 LDS-stage and R5 separate
// contiguous buffer both regressed — keep unified layout).
// Combined-denominator: one rcp per 4 d's; p *= den reused for ln-sum.
__global__ __launch_bounds__(256) void pair_kernel(
    const float4* __restrict__ msT4, float* __restrict__ out) {
  int L = blockIdx.x;
  int js = 0, base = 0;  // slab js has 64*(js+1) row-tiles of 2 rows
  while (L >= base + 64 * (js + 1)) { base += 64 * (js + 1); ++js; }
  const int ib = L - base;
  const int j0 = js * 128, i0 = ib * 2;
  const bool diag = (ib >= js * 64);  // tile straddles the diagonal
  const int t = threadIdx.x;
  const int lane = t & 127, h = t >> 7;  // h: which D-half
  const int j = j0 + lane;

  float acc[2] = {0.f, 0.f};
  float p[2] = {1.f, 1.f};
  int ea[2] = {0, 0};

#pragma unroll 4
  for (int gg = h * 32; gg < h * 32 + 32; ++gg) {  // 32 x 4 d's per half
    const float4 jva = msT4[(size_t)(2 * gg) * N + j];
    const float4 jvb = msT4[(size_t)(2 * gg + 1) * N + j];
#pragma unroll
    for (int k = 0; k < 2; ++k) {
      const float4 iva = msT4[(size_t)(2 * gg) * N + i0 + k];      // SGPR
      const float4 ivb = msT4[(size_t)(2 * gg + 1) * N + i0 + k];  // SGPR
      const float sa0 = iva.z + jva.z, sa1 = iva.w + jva.w;
      const float da0 = iva.x - jva.x, da1 = iva.y - jva.y;
      const float sb0 = ivb.z + jvb.z, sb1 = ivb.w + jvb.w;
      const float db0 = ivb.x - jvb.x, db1 = ivb.y - jvb.y;
      const float qa0 = da0 * da0, qa1 = da1 * da1;
      const float qb0 = db0 * db0, qb1 = db1 * db1;
      const float s01 = sa0 * sa1, s23 = sb0 * sb1;
      float na = qa0 * sa1; na = fmaf(qa1, sa0, na);
      float nb = qb0 * sb1; nb = fmaf(qb1, sb0, nb);
      float num = na * s23; num = fmaf(nb, s01, num);
      const float den = s01 * s23;
      acc[k] = fmaf(num, __builtin_amdgcn_rcpf(den), acc[k]);
      p[k] *= den;
    }
    if (gg & 1) {  // strip every 8 d's (16 strips per half, ends stripped)
#pragma unroll
      for (int k = 0; k < 2; ++k) {
        const int bb = __float_as_int(p[k]);
        ea[k] += bb >> 23;
        p[k] = __int_as_float((bb & 0x007fffff) | 0x3f800000);
      }
    }
  }

  constexpr float LN2 = 0.6931471805599453f;
  float part[2];
#pragma unroll
  for (int k = 0; k < 2; ++k) {
    const float lg2 = (float)(ea[k] - 127 * 16) + __log2f(p[k]);
    part[k] = acc[k] + LN2 * lg2;  // this half's additive contribution
  }

  __shared__ float sP[2][128];
  if (h) {
    sP[0][lane] = part[0];
    sP[1][lane] = part[1];
  }
  __syncthreads();
  if (!h) {
    float v[2];
    v[0] = -(part[0] + sP[0][lane]);
    v[1] = -(part[1] + sP[1][lane]);
    if (!diag) {  // strictly-upper tile: unmasked direct + mirror writes
      out[(size_t)i0 * N + j] = v[0];
      out[(size_t)(i0 + 1) * N + j] = v[1];
      *(float2*)(out + (size_t)j * N + i0) = make_float2(v[0], v[1]);
    } else {  // diagonal tile: per-element masks
#pragma unroll
      for (int k = 0; k < 2; ++k) {
        const int i = i0 + k;
        if (j >= i) out[(size_t)i * N + j] = v[k];
        if (j > i) out[(size_t)j * N + i] = v[k];
      }
    }
  }
}

extern "C" void kernel_launch(void* const* d_in, const int* in_sizes, int n_in,
                              void* d_out, int out_size, void* d_ws, size_t ws_size,
                              hipStream_t stream) {
  const float* muX = (const float*)d_in[0];
  const float* ls  = (const float*)d_in[1];
  float* out = (float*)d_out;
  float2* msT2 = (float2*)d_ws;  // [D/2][N][2] packed pairs = 2 MB
  prep3<<<dim3(N / RI), dim3(256), 0, stream>>>(muX, ls, msT2);
  const int nblocks = 64 * (8 * 9 / 2);  // 2304 triangular 2x128 tiles
  pair_kernel<<<dim3(nblocks), dim3(256), 0, stream>>>((const float4*)msT2,
                                                       out);
}

// Round 8
// 95.916 us; speedup vs baseline: 1.1797x; 1.1797x over previous
//
#include <hip/hip_runtime.h>

#define N 1024
#define D 256

// ---------------- prep ----------------
// Layout: msT2[(g*N+row)*2+b]: b=0 -> (mu_{2g},mu_{2g+1})*rden, b=1 -> (sig_{2g},sig_{2g+1})
// so pair's float4 read = (mu0, mu1, sig0, sig1) in natural 64-bit halves.
#define RI 8
#define LDW 260  // padded LDS row stride: %4==0 (float4 stores ok), +4 banks/row

__global__ __launch_bounds__(256) void prep3(
    const float* __restrict__ muX, const float* __restrict__ ls,
    float2* __restrict__ msT2) {
  const int i0 = blockIdx.x * RI;
  const int t = threadIdx.x;
  __shared__ float smu[RI][LDW];
  __shared__ float ssg[RI][LDW];
  __shared__ float rden[RI];
  const float4* mu4 = (const float4*)(muX + (size_t)i0 * D);
  const float4* ls4 = (const float4*)(ls + (size_t)i0 * D);
#pragma unroll
  for (int u = 0; u < 2; ++u) {
    const int idx = u * 256 + t;  // float4 index within the 8x256 row block
    const int row = idx >> 6, c4 = idx & 63;
    const float4 v = mu4[idx];
    *(float4*)&smu[row][c4 * 4] = v;
    const float4 e = ls4[idx];
    float4 x;
    x.x = __expf(e.x) + 5e-11f; x.y = __expf(e.y) + 5e-11f;  // eps folded
    x.z = __expf(e.z) + 5e-11f; x.w = __expf(e.w) + 5e-11f;
    *(float4*)&ssg[row][c4 * 4] = x;
  }
  __syncthreads();
  {
    const int r = t >> 5, q = t & 31;  // 32 lanes per row
    float s = 0.f;
#pragma unroll
    for (int k = 0; k < 8; ++k) {
      const float v = smu[r][q + 32 * k];
      s = fmaf(v, v, s);
    }
    // butterfly reduce within the 32-lane row group (replaces serial loop)
#pragma unroll
    for (int m = 16; m >= 1; m >>= 1) s += __shfl_xor(s, m, 32);
    if (q == 0) rden[r] = 1.0f / fmaxf(sqrtf(s), 1e-12f);  // F.normalize eps
  }
  __syncthreads();
#pragma unroll
  for (int pass = 0; pass < 8; ++pass) {
    const int f = pass * 256 + t;
    const int b = f & 1, il = (f >> 1) & 7, g = f >> 4;
    const float* src = b ? &ssg[il][0] : &smu[il][0];
    const float sc = b ? 1.0f : rden[il];
    msT2[((size_t)g * N + i0 + il) * 2 + b] =
        make_float2(src[2 * g] * sc, src[2 * g + 1] * sc);
  }
}

// ---------------- pair ----------------
// Triangular 4x128 tiles: 1152 blocks x 2 waves.
// R1-R7 lesson: the wall is L2 BANDWIDTH/contention (j-stream 590 MB at
// 2x128 tiles; every latency fix was neutral; stall/wave constant ~89K cy).
// k=4 i-rows halves j-traffic to 295 MB at unchanged total VALU issue.
// i-side: compile-time i0+k offsets -> wave-uniform s_loads from unified
// msT4 (R3 LDS / R5 separate buffer / R7 non-uniform all regressed).
// Combined-denominator: one rcp per 4 d's; p *= den reused for ln-sum.
__global__ __launch_bounds__(128) void pair_kernel(
    const float4* __restrict__ msT4, float* __restrict__ out) {
  int L = blockIdx.x;
  int js = 0, base = 0;  // slab js has 32*(js+1) row-tiles of 4 rows
  while (L >= base + 32 * (js + 1)) { base += 32 * (js + 1); ++js; }
  const int ib = L - base;
  const int j0 = js * 128, i0 = ib * 4;
  const bool diag = (ib >= js * 32);  // tile straddles the diagonal
  const int j = j0 + threadIdx.x;

  float acc[4] = {0.f, 0.f, 0.f, 0.f};
  float p[4] = {1.f, 1.f, 1.f, 1.f};
  int ea[4] = {0, 0, 0, 0};

#pragma unroll 2
  for (int gg = 0; gg < D / 4; ++gg) {  // 4 d's per iteration
    const float4 jva = msT4[(size_t)(2 * gg) * N + j];
    const float4 jvb = msT4[(size_t)(2 * gg + 1) * N + j];
#pragma unroll
    for (int k = 0; k < 4; ++k) {
      const float4 iva = msT4[(size_t)(2 * gg) * N + i0 + k];      // SGPR
      const float4 ivb = msT4[(size_t)(2 * gg + 1) * N + i0 + k];  // SGPR
      const float sa0 = iva.z + jva.z, sa1 = iva.w + jva.w;
      const float da0 = iva.x - jva.x, da1 = iva.y - jva.y;
      const float sb0 = ivb.z + jvb.z, sb1 = ivb.w + jvb.w;
      const float db0 = ivb.x - jvb.x, db1 = ivb.y - jvb.y;
      const float qa0 = da0 * da0, qa1 = da1 * da1;
      const float qb0 = db0 * db0, qb1 = db1 * db1;
      const float s01 = sa0 * sa1, s23 = sb0 * sb1;
      float na = qa0 * sa1; na = fmaf(qa1, sa0, na);
      float nb = qb0 * sb1; nb = fmaf(qb1, sb0, nb);
      float num = na * s23; num = fmaf(nb, s01, num);
      const float den = s01 * s23;
      acc[k] = fmaf(num, __builtin_amdgcn_rcpf(den), acc[k]);
      p[k] *= den;
    }
    if (gg & 1) {  // strip every 8 d's: |log2 p| bounded -> exponent safe
#pragma unroll
      for (int k = 0; k < 4; ++k) {
        const int bb = __float_as_int(p[k]);
        ea[k] += bb >> 23;
        p[k] = __int_as_float((bb & 0x007fffff) | 0x3f800000);
      }
    }
  }

  constexpr float LN2 = 0.6931471805599453f;
  float v[4];
#pragma unroll
  for (int k = 0; k < 4; ++k) {
    const float lg2 = (float)(ea[k] - 127 * (D / 8)) + __log2f(p[k]);
    v[k] = -(acc[k] + LN2 * lg2);
  }

  if (!diag) {  // strictly-upper tile: unmasked direct + float4 mirror
#pragma unroll
    for (int k = 0; k < 4; ++k) out[(size_t)(i0 + k) * N + j] = v[k];
    *(float4*)(out + (size_t)j * N + i0) =
        make_float4(v[0], v[1], v[2], v[3]);
  } else {  // diagonal tile: per-element masks
#pragma unroll
    for (int k = 0; k < 4; ++k) {
      const int i = i0 + k;
      if (j >= i) out[(size_t)i * N + j] = v[k];
      if (j > i) out[(size_t)j * N + i] = v[k];
    }
  }
}

extern "C" void kernel_launch(void* const* d_in, const int* in_sizes, int n_in,
                              void* d_out, int out_size, void* d_ws, size_t ws_size,
                              hipStream_t stream) {
  const float* muX = (const float*)d_in[0];
  const float* ls  = (const float*)d_in[1];
  float* out = (float*)d_out;
  float2* msT2 = (float2*)d_ws;  // [D/2][N][2] packed pairs = 2 MB
  prep3<<<dim3(N / RI), dim3(256), 0, stream>>>(muX, ls, msT2);
  const int nblocks = 32 * (8 * 9 / 2);  // 1152 triangular 4x128 tiles
  pair_kernel<<<dim3(nblocks), dim3(128), 0, stream>>>((const float4*)msT2,
                                                       out);
}

// Round 9
// 93.763 us; speedup vs baseline: 1.2067x; 1.0230x over previous
//
#include <hip/hip_runtime.h>

#define N 1024
#define D 256

// ---------------- prep ----------------
// Layout: msT2[(g*N+row)*2+b]: b=0 -> (mu_{2g},mu_{2g+1})*rden, b=1 -> (sig_{2g},sig_{2g+1})
// so pair's float4 read = (mu0, mu1, sig0, sig1) in natural 64-bit halves.
#define RI 8
#define LDW 260  // padded LDS row stride: %4==0 (float4 stores ok), +4 banks/row

__global__ __launch_bounds__(256) void prep3(
    const float* __restrict__ muX, const float* __restrict__ ls,
    float2* __restrict__ msT2) {
  const int i0 = blockIdx.x * RI;
  const int t = threadIdx.x;
  __shared__ float smu[RI][LDW];
  __shared__ float ssg[RI][LDW];
  __shared__ float sred[RI][32];
  __shared__ float rden[RI];
  const float4* mu4 = (const float4*)(muX + (size_t)i0 * D);
  const float4* ls4 = (const float4*)(ls + (size_t)i0 * D);
#pragma unroll
  for (int u = 0; u < 2; ++u) {
    const int idx = u * 256 + t;  // float4 index within the 8x256 row block
    const int row = idx >> 6, c4 = idx & 63;
    const float4 v = mu4[idx];
    *(float4*)&smu[row][c4 * 4] = v;
    const float4 e = ls4[idx];
    float4 x;
    x.x = __expf(e.x) + 5e-11f; x.y = __expf(e.y) + 5e-11f;  // eps folded
    x.z = __expf(e.z) + 5e-11f; x.w = __expf(e.w) + 5e-11f;
    *(float4*)&ssg[row][c4 * 4] = x;
  }
  __syncthreads();
  {
    const int r = t >> 5, q = t & 31;  // 32 lanes per row
    float s = 0.f;
#pragma unroll
    for (int k = 0; k < 8; ++k) {
      const float v = smu[r][q + 32 * k];
      s = fmaf(v, v, s);
    }
    sred[r][q] = s;
  }
  __syncthreads();
  if (t < RI) {
    float tot = 0.f;
    for (int u = 0; u < 32; ++u) tot += sred[t][u];
    rden[t] = 1.0f / fmaxf(sqrtf(tot), 1e-12f);  // F.normalize eps
  }
  __syncthreads();
#pragma unroll
  for (int pass = 0; pass < 8; ++pass) {
    const int f = pass * 256 + t;
    const int b = f & 1, il = (f >> 1) & 7, g = f >> 4;
    const float* src = b ? &ssg[il][0] : &smu[il][0];
    const float sc = b ? 1.0f : rden[il];
    msT2[((size_t)g * N + i0 + il) * 2 + b] =
        make_float2(src[2 * g] * sc, src[2 * g + 1] * sc);
  }
}

// ---------------- pair ----------------
// Triangular 2x128 tiles: 2304 blocks x 2 waves (R2 base, best at ~40us).
// NEW: per-block d-loop PHASE ROTATION. R1-R8 showed the wall (~42us) is
// invariant to VALU count, TLP, traffic, and prefetch — consistent with
// L2 bank hotspotting: all blocks march gg together, so the whole GPU
// reads the same 2 rows (32KB, 16KB-strided -> few banks) at any instant.
// gg = (it + (L&63)) & 63 spreads blocks over 64 row-pairs -> all banks.
// Legal: acc and p-product are order-invariant; strip on it&1 (32 strips).
// i-side wave-uniform s_loads (phase is blockIdx-only — R7 lesson).
__global__ __launch_bounds__(128) void pair_kernel(
    const float4* __restrict__ msT4, float* __restrict__ out) {
  int L = blockIdx.x;
  int js = 0, base = 0;  // slab js has 64*(js+1) row-tiles of 2 rows
  while (L >= base + 64 * (js + 1)) { base += 64 * (js + 1); ++js; }
  const int ib = L - base;
  const int j0 = js * 128, i0 = ib * 2;
  const bool diag = (ib >= js * 64);  // tile straddles the diagonal
  const int j = j0 + threadIdx.x;
  const int phase = L & 63;  // wave-uniform (SGPR) loop rotation

  float acc[2] = {0.f, 0.f};
  float p[2] = {1.f, 1.f};
  int ea[2] = {0, 0};

#pragma unroll 4
  for (int it = 0; it < D / 4; ++it) {  // 4 d's per iteration, rotated order
    const int gg = (it + phase) & 63;
    const float4 jva = msT4[(size_t)(2 * gg) * N + j];
    const float4 jvb = msT4[(size_t)(2 * gg + 1) * N + j];
#pragma unroll
    for (int k = 0; k < 2; ++k) {
      const float4 iva = msT4[(size_t)(2 * gg) * N + i0 + k];      // SGPR
      const float4 ivb = msT4[(size_t)(2 * gg + 1) * N + i0 + k];  // SGPR
      const float sa0 = iva.z + jva.z, sa1 = iva.w + jva.w;
      const float da0 = iva.x - jva.x, da1 = iva.y - jva.y;
      const float sb0 = ivb.z + jvb.z, sb1 = ivb.w + jvb.w;
      const float db0 = ivb.x - jvb.x, db1 = ivb.y - jvb.y;
      const float qa0 = da0 * da0, qa1 = da1 * da1;
      const float qb0 = db0 * db0, qb1 = db1 * db1;
      const float s01 = sa0 * sa1, s23 = sb0 * sb1;
      float na = qa0 * sa1; na = fmaf(qa1, sa0, na);
      float nb = qb0 * sb1; nb = fmaf(qb1, sb0, nb);
      float num = na * s23; num = fmaf(nb, s01, num);
      const float den = s01 * s23;
      acc[k] = fmaf(num, __builtin_amdgcn_rcpf(den), acc[k]);
      p[k] *= den;
    }
    if (it & 1) {  // strip every 8 d's: |log2 p| <= ~66 worst -> exponent safe
#pragma unroll
      for (int k = 0; k < 2; ++k) {
        const int bb = __float_as_int(p[k]);
        ea[k] += bb >> 23;
        p[k] = __int_as_float((bb & 0x007fffff) | 0x3f800000);
      }
    }
  }

  constexpr float LN2 = 0.6931471805599453f;
  float v[2];
#pragma unroll
  for (int k = 0; k < 2; ++k) {
    const float lg2 = (float)(ea[k] - 127 * (D / 8)) + __log2f(p[k]);
    v[k] = -(acc[k] + LN2 * lg2);
  }

  if (!diag) {  // strictly-upper tile: unmasked direct + mirror writes
    out[(size_t)i0 * N + j] = v[0];
    out[(size_t)(i0 + 1) * N + j] = v[1];
    *(float2*)(out + (size_t)j * N + i0) = make_float2(v[0], v[1]);
  } else {  // diagonal tile: per-element masks
#pragma unroll
    for (int k = 0; k < 2; ++k) {
      const int i = i0 + k;
      if (j >= i) out[(size_t)i * N + j] = v[k];
      if (j > i) out[(size_t)j * N + i] = v[k];
    }
  }
}

extern "C" void kernel_launch(void* const* d_in, const int* in_sizes, int n_in,
                              void* d_out, int out_size, void* d_ws, size_t ws_size,
                              hipStream_t stream) {
  const float* muX = (const float*)d_in[0];
  const float* ls  = (const float*)d_in[1];
  float* out = (float*)d_out;
  float2* msT2 = (float2*)d_ws;  // [D/2][N][2] packed pairs = 2 MB
  prep3<<<dim3(N / RI), dim3(256), 0, stream>>>(muX, ls, msT2);
  const int nblocks = 64 * (8 * 9 / 2);  // 2304 triangular 2x128 tiles
  pair_kernel<<<dim3(nblocks), dim3(128), 0, stream>>>((const float4*)msT2,
                                                       out);
}

// Round 10
// 89.314 us; speedup vs baseline: 1.2669x; 1.0498x over previous
//
#include <hip/hip_runtime.h>

#define N 1024
#define D 256

// ---------------- prep ----------------
// Layout: msT2[(g*N+row)*2+b]: b=0 -> (mu_{2g},mu_{2g+1})*rden, b=1 -> (sig_{2g},sig_{2g+1})
// so pair's float4 read = (mu0, mu1, sig0, sig1) in natural 64-bit halves.
#define RI 8
#define LDW 260  // padded LDS row stride: %4==0 (float4 stores ok), +4 banks/row

__global__ __launch_bounds__(256) void prep3(
    const float* __restrict__ muX, const float* __restrict__ ls,
    float2* __restrict__ msT2) {
  const int i0 = blockIdx.x * RI;
  const int t = threadIdx.x;
  __shared__ float smu[RI][LDW];
  __shared__ float ssg[RI][LDW];
  __shared__ float rden[RI];
  const float4* mu4 = (const float4*)(muX + (size_t)i0 * D);
  const float4* ls4 = (const float4*)(ls + (size_t)i0 * D);
#pragma unroll
  for (int u = 0; u < 2; ++u) {
    const int idx = u * 256 + t;  // float4 index within the 8x256 row block
    const int row = idx >> 6, c4 = idx & 63;
    const float4 v = mu4[idx];
    *(float4*)&smu[row][c4 * 4] = v;
    const float4 e = ls4[idx];
    float4 x;
    x.x = __expf(e.x) + 5e-11f; x.y = __expf(e.y) + 5e-11f;  // eps folded
    x.z = __expf(e.z) + 5e-11f; x.w = __expf(e.w) + 5e-11f;
    *(float4*)&ssg[row][c4 * 4] = x;
  }
  __syncthreads();
  {
    const int r = t >> 5, q = t & 31;  // 32 lanes per row
    float s = 0.f;
#pragma unroll
    for (int k = 0; k < 8; ++k) {
      const float v = smu[r][q + 32 * k];
      s = fmaf(v, v, s);
    }
    // butterfly reduce within the 32-lane row group (R8: verified passing;
    // removes the 8-thread serial 32-iter chain + sred LDS + one barrier)
#pragma unroll
    for (int m = 16; m >= 1; m >>= 1) s += __shfl_xor(s, m, 32);
    if (q == 0) rden[r] = 1.0f / fmaxf(sqrtf(s), 1e-12f);  // F.normalize eps
  }
  __syncthreads();
#pragma unroll
  for (int pass = 0; pass < 8; ++pass) {
    const int f = pass * 256 + t;
    const int b = f & 1, il = (f >> 1) & 7, g = f >> 4;
    const float* src = b ? &ssg[il][0] : &smu[il][0];
    const float sc = b ? 1.0f : rden[il];
    msT2[((size_t)g * N + i0 + il) * 2 + b] =
        make_float2(src[2 * g] * sc, src[2 * g + 1] * sc);
  }
}

// ---------------- pair ----------------
// Triangular 2x128 tiles, D-SPLIT: 2304 blocks x 4 waves (256 thr).
// Waves 0-1 (h=0) do d[0,128), waves 2-3 (h=1) do d[128,256); both acc and
// the ln-term are additive over d -> exact split, combined via 1KB LDS.
// R7 ran this but h = t>>7 wasn't provably wave-uniform: compiler demoted
// i-side reads to per-lane VMEM (VGPR 60, busy doubled). FIX: readfirstlane
// pins h in an SGPR -> i-addresses stay SALU -> s_load_dwordx4 preserved.
// This is the clean TLP test R1-R9 never ran (occupancy pinned ~27% = ~2.2
// waves/SIMD; the ~40us wall is invariant to VALU, traffic, prefetch).
// Combined-denominator: one rcp per 4 d's; p *= den reused for ln-sum.
__global__ __launch_bounds__(256) void pair_kernel(
    const float4* __restrict__ msT4, float* __restrict__ out) {
  int L = blockIdx.x;
  int js = 0, base = 0;  // slab js has 64*(js+1) row-tiles of 2 rows
  while (L >= base + 64 * (js + 1)) { base += 64 * (js + 1); ++js; }
  const int ib = L - base;
  const int j0 = js * 128, i0 = ib * 2;
  const bool diag = (ib >= js * 64);  // tile straddles the diagonal
  const int t = threadIdx.x;
  const int lane = t & 127;
  const int h = __builtin_amdgcn_readfirstlane(t >> 7);  // SGPR D-half id
  const int j = j0 + lane;

  float acc[2] = {0.f, 0.f};
  float p[2] = {1.f, 1.f};
  int ea[2] = {0, 0};

#pragma unroll 4
  for (int it = 0; it < 32; ++it) {  // 32 x 4 d's per half
    const int gg = h * 32 + it;      // SGPR + loop counter -> SALU
    const float4 jva = msT4[(size_t)(2 * gg) * N + j];
    const float4 jvb = msT4[(size_t)(2 * gg + 1) * N + j];
#pragma unroll
    for (int k = 0; k < 2; ++k) {
      const float4 iva = msT4[(size_t)(2 * gg) * N + i0 + k];      // s_load
      const float4 ivb = msT4[(size_t)(2 * gg + 1) * N + i0 + k];  // s_load
      const float sa0 = iva.z + jva.z, sa1 = iva.w + jva.w;
      const float da0 = iva.x - jva.x, da1 = iva.y - jva.y;
      const float sb0 = ivb.z + jvb.z, sb1 = ivb.w + jvb.w;
      const float db0 = ivb.x - jvb.x, db1 = ivb.y - jvb.y;
      const float qa0 = da0 * da0, qa1 = da1 * da1;
      const float qb0 = db0 * db0, qb1 = db1 * db1;
      const float s01 = sa0 * sa1, s23 = sb0 * sb1;
      float na = qa0 * sa1; na = fmaf(qa1, sa0, na);
      float nb = qb0 * sb1; nb = fmaf(qb1, sb0, nb);
      float num = na * s23; num = fmaf(nb, s01, num);
      const float den = s01 * s23;
      acc[k] = fmaf(num, __builtin_amdgcn_rcpf(den), acc[k]);
      p[k] *= den;
    }
    if (it & 1) {  // strip every 8 d's: 16 strips per half, exponent safe
#pragma unroll
      for (int k = 0; k < 2; ++k) {
        const int bb = __float_as_int(p[k]);
        ea[k] += bb >> 23;
        p[k] = __int_as_float((bb & 0x007fffff) | 0x3f800000);
      }
    }
  }

  constexpr float LN2 = 0.6931471805599453f;
  float part[2];
#pragma unroll
  for (int k = 0; k < 2; ++k) {
    const float lg2 = (float)(ea[k] - 127 * 16) + __log2f(p[k]);
    part[k] = acc[k] + LN2 * lg2;  // this half's additive contribution
  }

  __shared__ float sP[2][128];
  if (h) {
    sP[0][lane] = part[0];
    sP[1][lane] = part[1];
  }
  __syncthreads();
  if (!h) {
    float v[2];
    v[0] = -(part[0] + sP[0][lane]);
    v[1] = -(part[1] + sP[1][lane]);
    if (!diag) {  // strictly-upper tile: unmasked direct + mirror writes
      out[(size_t)i0 * N + j] = v[0];
      out[(size_t)(i0 + 1) * N + j] = v[1];
      *(float2*)(out + (size_t)j * N + i0) = make_float2(v[0], v[1]);
    } else {  // diagonal tile: per-element masks
#pragma unroll
      for (int k = 0; k < 2; ++k) {
        const int i = i0 + k;
        if (j >= i) out[(size_t)i * N + j] = v[k];
        if (j > i) out[(size_t)j * N + i] = v[k];
      }
    }
  }
}

extern "C" void kernel_launch(void* const* d_in, const int* in_sizes, int n_in,
                              void* d_out, int out_size, void* d_ws, size_t ws_size,
                              hipStream_t stream) {
  const float* muX = (const float*)d_in[0];
  const float* ls  = (const float*)d_in[1];
  float* out = (float*)d_out;
  float2* msT2 = (float2*)d_ws;  // [D/2][N][2] packed pairs = 2 MB
  prep3<<<dim3(N / RI), dim3(256), 0, stream>>>(muX, ls, msT2);
  const int nblocks = 64 * (8 * 9 / 2);  // 2304 triangular 2x128 tiles
  pair_kernel<<<dim3(nblocks), dim3(256), 0, stream>>>((const float4*)msT2,
                                                       out);
}